// Round 17
// baseline (100.532 us; speedup 1.0000x reference)
//
#include <hip/hip_runtime.h>
#include <hip/hip_bf16.h>
#include <math.h>

typedef __attribute__((ext_vector_type(8))) short bf16x8;
typedef __attribute__((ext_vector_type(4))) float f32x4;
typedef __attribute__((ext_vector_type(8))) _Float16 h8;
typedef unsigned long long u64;

#define NSAMP  128000
#define TFR    501
#define TP     512         // padded t-stride of power planes
#define FPOW   257
#define NF     257
#define B_SZ   64
#define CHUNKT 32
#define NCH    16
#define EPS_F  1.1920928955078125e-07f

#define ASEGB  65536       // 64 frames x 1024B ([s_e 512B | s_o 512B])
#define BGRPB  131072      // one parity group: 8 ph x 16 colgrp x 1024B
#define BPHB2  16384       // per-phase per-group tile: 16 colgrp x 1024B

// ---- folded basis, [grp(2)][ph(8)][colgrp(16)][lane(64)][8 bf16] --------
// Within group: cc 0..255, eo = (cc>>5)*16 + (cc&15), isIm = (cc>>4)&1;
// grp0: bin = 2*eo (K=256 vs s_e); grp1: bin = 2*eo+1 (vs s_o).
// grp0 cc==16 (dead im of DC) hosts Nyquist basis (-1)^m.
// NO window here (window folded into A). Also builds 512-entry w table.
__global__ __launch_bounds__(256)
void build_basis(unsigned short* __restrict__ Bt, float* __restrict__ wtab) {
    int c = blockIdx.x;          // 0..511
    int grp = c >> 8, cc = c & 255;
    int eo = (cc >> 5) * 16 + (cc & 15);
    int isIm = (cc >> 4) & 1;
    int bin = grp ? (2 * eo + 1) : (2 * eo);
    int m = threadIdx.x;         // 0..255
    float v;
    if (grp == 0 && cc == 16) {
        v = (m & 1) ? -1.f : 1.f;               // Nyquist: (-1)^m vs s_e
    } else {
        int mm = (bin * m) & 511;
        float th = (float)mm * (float)(2.0 * M_PI / 512.0);
        v = isIm ? -sinf(th) : cosf(th);
    }
    __hip_bfloat16 h = __float2bfloat16(v);
    int ph = m >> 5, cg16 = cc >> 4;
    int lane = ((m >> 3) & 3) * 16 + (cc & 15);
    size_t idx = (((size_t)(grp * 8 + ph) * 16 + cg16) * 64 + lane) * 8 + (m & 7);
    Bt[idx] = *reinterpret_cast<unsigned short*>(&h);
    if (c == 0) {
        wtab[m]       = sinf((float)m * (float)(M_PI / 512.0));
        wtab[m + 256] = sinf((float)(m + 256) * (float)(M_PI / 512.0));
    }
}

// ---- MFMA DFT GEMM v17: even/odd fold, K=256, r15 schedule --------------
// grid (8 mchunk, 64 b, 2 s) = 1024 blocks, block 512 (8 waves).
// Waves 0..3 compute even bins (A = s_e half), 4..7 odd bins (s_o half).
// Wave tile 64 rows x 64 cols, acc[4][4]; 8 phases of K=32; B from L2 to
// regs with copy-free ping-pong prefetch; barrier-free K-loop.
__global__ __launch_bounds__(512)
void dft_gemm(const float* __restrict__ sig,
              const float* __restrict__ intf,
              const unsigned short* __restrict__ Bt,
              const float* __restrict__ wtab,
              _Float16* __restrict__ powo)
{
    __shared__ char As[ASEGB];

    const int mchunk = blockIdx.x, b = blockIdx.y, s = blockIdx.z;
    const int tid = threadIdx.x, lane = tid & 63, wn = tid >> 6;  // 8 waves
    const int lq = lane >> 4, ll = lane & 15;
    const float* x = (s == 0 ? intf : sig) + (size_t)b * NSAMP;
    const int tbase = mchunk * 16384 - 256;

    // ---- A staging: windowed + even/odd folded frames, swizzled ----
    {
        const int f = tid >> 3, sub = tid & 7;
        const int base = tbase + f * 256;
        #pragma unroll
        for (int i = 0; i < 8; ++i) {
            const int m = sub * 32 + i * 4;
            const int p0 = base + m;
            float xa[4], xb[4];
            if (p0 >= 0 && p0 + 260 <= NSAMP) {
                float4 va = *(const float4*)(x + p0);
                float4 vb = *(const float4*)(x + p0 + 256);
                xa[0]=va.x; xa[1]=va.y; xa[2]=va.z; xa[3]=va.w;
                xb[0]=vb.x; xb[1]=vb.y; xb[2]=vb.z; xb[3]=vb.w;
            } else {
                #pragma unroll
                for (int e = 0; e < 4; ++e) {
                    int p = p0 + e;
                    if (p < 0) p = -p;
                    if (p >= NSAMP) p = 2 * NSAMP - 2 - p;
                    xa[e] = x[p];
                    int q = p0 + 256 + e;
                    if (q >= NSAMP) q = 2 * NSAMP - 2 - q;
                    xb[e] = x[q];
                }
            }
            float4 wa = *(const float4*)(wtab + m);
            float4 wb = *(const float4*)(wtab + m + 256);
            float w0[4] = {wa.x, wa.y, wa.z, wa.w};
            float w1[4] = {wb.x, wb.y, wb.z, wb.w};
            unsigned short he[4], ho[4];
            #pragma unroll
            for (int e = 0; e < 4; ++e) {
                float pa = xa[e] * w0[e];
                float pb = xb[e] * w1[e];
                __hip_bfloat16 t0 = __float2bfloat16(pa + pb);
                __hip_bfloat16 t1 = __float2bfloat16(pa - pb);
                he[e] = *(unsigned short*)&t0;
                ho[e] = *(unsigned short*)&t1;
            }
            u64 pe = (u64)he[0] | ((u64)he[1] << 16) |
                     ((u64)he[2] << 32) | ((u64)he[3] << 48);
            u64 po = (u64)ho[0] | ((u64)ho[1] << 16) |
                     ((u64)ho[2] << 32) | ((u64)ho[3] << 48);
            int ae = f * 1024 + m * 2;
            int ao = ae + 512;
            ae ^= ((ae >> 10) & 7) << 4;
            ao ^= ((ao >> 10) & 7) << 4;
            *(u64*)(As + ae) = pe;
            *(u64*)(As + ao) = po;
        }
    }
    __syncthreads();    // the ONLY barrier: A ready; K-loop free-runs

    f32x4 acc[4][4];
    #pragma unroll
    for (int i = 0; i < 4; ++i)
        #pragma unroll
        for (int j = 0; j < 4; ++j) acc[i][j] = 0;

    const int grp = wn >> 2;            // 0: even bins (s_e), 1: odd (s_o)
    const int grpoff = grp * 512;       // byte offset into A row
    const char* WB = (const char*)Bt + (size_t)grp * BGRPB
                   + (wn & 3) * 4096 + lane * 16;

    bf16x8 B0[4], B1[4];

    auto loadPh = [&](int ph, bf16x8 (&dst)[4]) {
        const char* bp = WB + (size_t)ph * BPHB2;
        #pragma unroll
        for (int nf = 0; nf < 4; ++nf)
            dst[nf] = *(const bf16x8*)(bp + nf * 1024);
    };

    auto doPhase = [&](int ph, bf16x8 (&cur)[4]) {
        bf16x8 af[4];
        #pragma unroll
        for (int mf = 0; mf < 4; ++mf) {
            int a = (mf * 16 + ll) * 1024 + grpoff + ph * 64 + lq * 16;
            a ^= ((a >> 10) & 7) << 4;
            af[mf] = *(const bf16x8*)(As + a);
        }
        __builtin_amdgcn_s_setprio(1);
        #pragma unroll
        for (int mf = 0; mf < 4; ++mf)
            #pragma unroll
            for (int nf = 0; nf < 4; ++nf)
                acc[mf][nf] = __builtin_amdgcn_mfma_f32_16x16x32_bf16(
                    af[mf], cur[nf], acc[mf][nf], 0, 0, 0);
        __builtin_amdgcn_s_setprio(0);
    };

    loadPh(0, B0);
    #pragma unroll 1
    for (int pp2 = 0; pp2 < 4; ++pp2) {
        const int ph = pp2 * 2;
        loadPh(ph + 1, B1);                 // prefetch odd phase
        doPhase(ph, B0);                    // compute even phase
        if (pp2 < 3) loadPh(ph + 2, B0);    // prefetch next even phase
        doPhase(ph + 1, B1);                // compute odd phase
    }

    // ---- epilogue: power = re^2 + im^2, t-major fp16, packed u64 stores ----
    const int sb = s * 64 + b;
    _Float16* pbase = powo + (size_t)sb * FPOW * TP;
    #pragma unroll
    for (int mf = 0; mf < 4; ++mf) {
        const int rl0 = mchunk * 64 + mf * 16 + lq * 4;
        #pragma unroll
        for (int p = 0; p < 2; ++p) {
            f32x4 re = acc[mf][2 * p], im = acc[mf][2 * p + 1];
            int gb = (wn & 3) * 2 + p;
            int eo = gb * 16 + ll;
            int bin = grp ? (2 * eo + 1) : (2 * eo);
            bool nyq = (grp == 0) && (gb == 0) && (ll == 0);
            unsigned short hp[4], hn[4];
            #pragma unroll
            for (int j = 0; j < 4; ++j) {
                float pr = re[j] * re[j];
                float pi = im[j] * im[j];
                _Float16 hv = (_Float16)(nyq ? pr : (pr + pi));
                hp[j] = *(unsigned short*)&hv;
                _Float16 hw = (_Float16)pi;
                hn[j] = *(unsigned short*)&hw;
            }
            u64 pk = (u64)hp[0] | ((u64)hp[1] << 16) |
                     ((u64)hp[2] << 32) | ((u64)hp[3] << 48);
            *(u64*)(pbase + (size_t)bin * TP + rl0) = pk;
            if (nyq) {
                u64 pk2 = (u64)hn[0] | ((u64)hn[1] << 16) |
                          ((u64)hn[2] << 32) | ((u64)hn[3] << 48);
                *(u64*)(pbase + (size_t)256 * TP + rl0) = pk2;
            }
        }
    }
}

// ---- warm-up: vectorized fp16 loads, static indexing --------------------
template<int W>
__device__ __forceinline__ float warm_fixed(const _Float16* __restrict__ nrow,
                                            int base, float alpha, float oma) {
    h8 blk[W / 8];
    #pragma unroll
    for (int i = 0; i < W / 8; ++i)
        blk[i] = *(const h8*)(nrow + base + i * 8);
    float v = (float)blk[0][0];
    #pragma unroll
    for (int i = 1; i < W; ++i)
        v = fmaf(alpha, v, oma * (float)blk[i / 8][i % 8]);
    v = fmaf(alpha, v, oma * (float)nrow[base + W]);
    return v;
}

// ---- chunked IIR scan + SPP + MSE, t-major fp16 planes ------------------
__global__ __launch_bounds__(256, 4)
void spp_loss_kernel(const _Float16* __restrict__ noiseP,
                     const _Float16* __restrict__ noisyP,
                     const float* __restrict__ est,
                     float* __restrict__ out,
                     float alpha)
{
    const double XI = 31.622776601683793;
    const float RATIO = (float)(1.0 + XI);
    const float COEF  = (float)(XI / (1.0 + XI));
    const float INVN  = (float)(1.0 / ((double)B_SZ * NF * TFR));

    int tid = blockIdx.x * blockDim.x + threadIdx.x;
    int f   = tid % NF;
    int rem = tid / NF;
    int c   = rem & (NCH - 1);
    int b   = rem >> 4;

    float local = 0.f;
    if (b < B_SZ) {
        const int t0   = c * CHUNKT;
        const int tend = min(TFR, t0 + CHUNKT);
        const _Float16* nrow = noiseP + ((size_t)b * NF + f) * TP;
        const _Float16* yrow = noisyP + ((size_t)b * NF + f) * TP;
        const float* erow = est + ((size_t)b * NF + f) * TFR;
        const float oma = 1.f - alpha;

        float v;
        if (t0 == 0)            v = (float)nrow[0];
        else if (t0 == CHUNKT)  v = warm_fixed<32>(nrow, 0, alpha, oma);
        else                    v = warm_fixed<48>(nrow, t0 - 48, alpha, oma);

        h8 wn8[4], wy8[4];
        #pragma unroll
        for (int i = 0; i < 4; ++i) {
            wn8[i] = *(const h8*)(nrow + t0 + i * 8);
            wy8[i] = *(const h8*)(yrow + t0 + i * 8);
        }
        float last_n = (float)nrow[t0 + 32];
        float last_y = (float)yrow[t0 + 32];
        float qe[32];
        #pragma unroll
        for (int i = 0; i < 32; ++i)
            qe[i] = erow[min(t0 + 1 + i, TFR - 1)];

        {
            float np = (float)wy8[0][0];
            float e0 = erow[t0];
            float expo = -np / (v + EPS_F) * COEF;
            float spp  = 1.f / fmaf(RATIO, __expf(expo), 1.f);
            float d = e0 - spp;
            local = fmaf(d, d, local);
        }
        #pragma unroll
        for (int i = 0; i < 32; ++i) {
            int t = t0 + 1 + i;
            float nv = (i < 31) ? (float)wn8[(i + 1) / 8][(i + 1) % 8] : last_n;
            v = fmaf(alpha, v, oma * nv);
            if (t < tend) {
                float yv = (i < 31) ? (float)wy8[(i + 1) / 8][(i + 1) % 8] : last_y;
                float expo = -yv / (v + EPS_F) * COEF;
                float spp  = 1.f / fmaf(RATIO, __expf(expo), 1.f);
                float d = qe[i] - spp;
                local = fmaf(d, d, local);
            }
        }
    }

    for (int off = 32; off > 0; off >>= 1)
        local += __shfl_down(local, off);
    __shared__ float wsum[4];
    if ((threadIdx.x & 63) == 0) wsum[threadIdx.x >> 6] = local;
    __syncthreads();
    if (threadIdx.x == 0) {
        float ssum = (wsum[0] + wsum[1]) + (wsum[2] + wsum[3]);
        atomicAdd(out, ssum * INVN);
    }
}

extern "C" void kernel_launch(void* const* d_in, const int* in_sizes, int n_in,
                              void* d_out, int out_size, void* d_ws, size_t ws_size,
                              hipStream_t stream) {
    const float* est  = (const float*)d_in[0];   // spp_estimate (B,1,F,T)
    const float* sig  = (const float*)d_in[1];   // input_sig    (B,1,N)
    const float* intf = (const float*)d_in[2];   // interference (B,1,N)

    unsigned short* Bt = (unsigned short*)d_ws;                    // 256 KB basis
    float* wtab = (float*)((char*)d_ws + (size_t)256 * 1024);      // 2 KB window
    _Float16* powp = (_Float16*)((char*)d_ws + (size_t)512 * 1024);

    hipLaunchKernelGGL(build_basis, dim3(512), dim3(256), 0, stream, Bt, wtab);
    hipMemsetAsync(d_out, 0, sizeof(float), stream);

    dim3 gG(8, 64, 2);
    hipLaunchKernelGGL(dft_gemm, gG, dim3(512), 0, stream,
                       sig, intf, Bt, wtab, powp);

    const double alpha_d = exp(-((double)256) / (16000.0 * 0.072));
    const _Float16* noiseP = powp;                            // sb 0..63
    const _Float16* noisyP = powp + (size_t)B_SZ * FPOW * TP; // sb 64..127
    dim3 gB((B_SZ * NCH * NF + 255) / 256);
    hipLaunchKernelGGL(spp_loss_kernel, gB, dim3(256), 0, stream,
                       noiseP, noisyP, est, (float*)d_out, (float)alpha_d);
}

// Round 18
// 99.154 us; speedup vs baseline: 1.0139x; 1.0139x over previous
//
#include <hip/hip_runtime.h>
#include <hip/hip_bf16.h>
#include <math.h>

typedef __attribute__((ext_vector_type(8))) short bf16x8;
typedef __attribute__((ext_vector_type(4))) float f32x4;
typedef __attribute__((ext_vector_type(8))) _Float16 h8;
typedef unsigned long long u64;

#define NSAMP  128000
#define TFR    501
#define TP     512         // padded t-stride of power planes
#define FPOW   257
#define NF     257
#define B_SZ   64
#define CHUNKT 32
#define NCH    16
#define EPS_F  1.1920928955078125e-07f

#define SEG    16640       // 64*256 + 256 samples per 64-frame chunk
#define SEGB   33280       // SEG * 2 bytes (bf16)
#define BPHB   32768       // one K=32 phase of basis: 512 cols = 32 KB

// ---- basis, layout [ph(16)][colgrp(32)][lane(64)][8 bf16] ---------------
// col = colgrp*16 + (lane&15); k = ph*32 + (lane>>4)*8 + j.
// col semantic: (bin>>4)*32 + isIm*16 + (bin&15); col 16 = Nyquist basis.
__global__ __launch_bounds__(256)
void build_basis(unsigned short* __restrict__ Bt) {
    int col = blockIdx.x;
    int g = col >> 5, o = col & 15;
    int isIm = (col >> 4) & 1;
    int bin = g * 16 + o;
    for (int k = threadIdx.x; k < 512; k += 256) {
        float w = sinf((float)k * (float)(M_PI / 512.0));   // sqrt-hann
        float v;
        if (col == 16) {
            v = w * ((k & 1) ? -1.f : 1.f);
        } else {
            int mm = (bin * k) & 511;
            float th = (float)mm * (float)(2.0 * M_PI / 512.0);
            v = w * (isIm ? -sinf(th) : cosf(th));
        }
        __hip_bfloat16 h = __float2bfloat16(v);
        int ph = k >> 5, kq = (k >> 3) & 3, j = k & 7;
        size_t idx = (((size_t)ph * 32 + (col >> 4)) * 64
                      + kq * 16 + (col & 15)) * 8 + j;
        Bt[idx] = *reinterpret_cast<unsigned short*>(&h);
    }
}

// ---- MFMA DFT GEMM v18: 64x32 wave tile, high occupancy -----------------
// grid (16 = 8 mchunk x 2 nhalf, 64 b, 2 s) = 2048 blocks, block 512.
// 8 waves, each owns ONE re/im col pair (32 cols); acc[4][2] = 32 acc regs
// -> ~96-100 total regs/wave -> 5-6 waves/SIMD: phase wall > L2 latency,
// prefetch-1 covers. B traffic unchanged (512 MB), A dup x2 (L3-absorbed).
__global__ __launch_bounds__(512)
void dft_gemm(const float* __restrict__ sig,
              const float* __restrict__ intf,
              const unsigned short* __restrict__ Bt,
              _Float16* __restrict__ powo)
{
    __shared__ char As[SEGB];

    const int mchunk = blockIdx.x >> 1, nh = blockIdx.x & 1;
    const int b = blockIdx.y, s = blockIdx.z;
    const int tid = threadIdx.x, lane = tid & 63, wn = tid >> 6;  // 8 waves
    const int lq = lane >> 4, ll = lane & 15;
    const float* x = (s == 0 ? intf : sig) + (size_t)b * NSAMP;
    const int tbase = mchunk * 16384 - 256;

    // ---- A staging: contiguous segment, float4, bf16, addr-XOR swizzle ----
    {
        const int jlo = (tbase < 0) ? -tbase : 0;
        const int jhi = (tbase + SEG > NSAMP) ? (NSAMP - tbase) : SEG;
        for (int i = tid; i < SEG / 4; i += 512) {
            int j = i * 4;
            float f0, f1, f2, f3;
            if (j >= jlo && j + 4 <= jhi) {
                float4 v = *(const float4*)(x + tbase + j);
                f0 = v.x; f1 = v.y; f2 = v.z; f3 = v.w;
            } else {
                int p0 = tbase + j;
                int pp[4];
                #pragma unroll
                for (int e = 0; e < 4; ++e) {
                    int p = p0 + e;
                    if (p < 0) p = -p;
                    if (p >= NSAMP) p = 2 * NSAMP - 2 - p;
                    pp[e] = p;
                }
                f0 = x[pp[0]]; f1 = x[pp[1]]; f2 = x[pp[2]]; f3 = x[pp[3]];
            }
            unsigned short h[4];
            __hip_bfloat16 t0 = __float2bfloat16(f0); h[0] = *(unsigned short*)&t0;
            __hip_bfloat16 t1 = __float2bfloat16(f1); h[1] = *(unsigned short*)&t1;
            __hip_bfloat16 t2 = __float2bfloat16(f2); h[2] = *(unsigned short*)&t2;
            __hip_bfloat16 t3 = __float2bfloat16(f3); h[3] = *(unsigned short*)&t3;
            u64 pk = (u64)h[0] | ((u64)h[1] << 16) |
                     ((u64)h[2] << 32) | ((u64)h[3] << 48);
            int a = i * 8;
            a ^= ((a >> 9) & 7) << 4;
            *(u64*)(As + a) = pk;
        }
    }
    __syncthreads();    // the ONLY barrier: A ready; K-loop free-runs

    f32x4 acc[4][2];
    #pragma unroll
    for (int i = 0; i < 4; ++i)
        #pragma unroll
        for (int j = 0; j < 2; ++j) acc[i][j] = 0;

    // per-lane byte base into basis for this wave's re/im col pair
    const char* bb = (const char*)Bt
                   + (size_t)((nh * 16 + wn * 2) * 64 + lane) * 16;

    bf16x8 B0[2], B1[2];

    auto loadPh = [&](int ph, bf16x8 (&dst)[2]) {
        const char* bp = bb + (size_t)ph * BPHB;
        dst[0] = *(const bf16x8*)(bp);
        dst[1] = *(const bf16x8*)(bp + 1024);
    };

    auto doPhase = [&](int ph, bf16x8 (&cur)[2]) {
        bf16x8 af[4];
        #pragma unroll
        for (int mf = 0; mf < 4; ++mf) {
            int a = (mf * 16 + ll) * 512 + ph * 64 + lq * 16;
            a ^= ((a >> 9) & 7) << 4;
            af[mf] = *(const bf16x8*)(As + a);
        }
        __builtin_amdgcn_s_setprio(1);
        #pragma unroll
        for (int mf = 0; mf < 4; ++mf)
            #pragma unroll
            for (int nf = 0; nf < 2; ++nf)
                acc[mf][nf] = __builtin_amdgcn_mfma_f32_16x16x32_bf16(
                    af[mf], cur[nf], acc[mf][nf], 0, 0, 0);
        __builtin_amdgcn_s_setprio(0);
    };

    loadPh(0, B0);
    #pragma unroll 1
    for (int pp2 = 0; pp2 < 8; ++pp2) {
        const int ph = pp2 * 2;
        loadPh(ph + 1, B1);                 // prefetch odd phase
        doPhase(ph, B0);                    // compute even phase
        if (pp2 < 7) loadPh(ph + 2, B0);    // prefetch next even phase
        doPhase(ph + 1, B1);                // compute odd phase
    }

    // ---- epilogue: power = re^2 + im^2, t-major fp16, packed u64 stores ----
    const int sb = s * 64 + b;
    _Float16* pbase = powo + (size_t)sb * FPOW * TP;
    const int gbin = nh * 8 + wn;           // this wave's 16-bin group
    const int bin = gbin * 16 + ll;
    const bool nyq = (gbin == 0) && (ll == 0);
    #pragma unroll
    for (int mf = 0; mf < 4; ++mf) {
        const int rl0 = mchunk * 64 + mf * 16 + lq * 4;
        f32x4 re = acc[mf][0], im = acc[mf][1];
        unsigned short hp[4], hn[4];
        #pragma unroll
        for (int j = 0; j < 4; ++j) {
            float pr = re[j] * re[j];
            float pi = im[j] * im[j];
            _Float16 hv = (_Float16)(nyq ? pr : (pr + pi));
            hp[j] = *(unsigned short*)&hv;
            _Float16 hw = (_Float16)pi;
            hn[j] = *(unsigned short*)&hw;
        }
        u64 pk = (u64)hp[0] | ((u64)hp[1] << 16) |
                 ((u64)hp[2] << 32) | ((u64)hp[3] << 48);
        *(u64*)(pbase + (size_t)bin * TP + rl0) = pk;
        if (nyq) {
            u64 pk2 = (u64)hn[0] | ((u64)hn[1] << 16) |
                      ((u64)hn[2] << 32) | ((u64)hn[3] << 48);
            *(u64*)(pbase + (size_t)256 * TP + rl0) = pk2;
        }
    }
}

// ---- warm-up: vectorized fp16 loads, static indexing --------------------
template<int W>
__device__ __forceinline__ float warm_fixed(const _Float16* __restrict__ nrow,
                                            int base, float alpha, float oma) {
    h8 blk[W / 8];
    #pragma unroll
    for (int i = 0; i < W / 8; ++i)
        blk[i] = *(const h8*)(nrow + base + i * 8);
    float v = (float)blk[0][0];
    #pragma unroll
    for (int i = 1; i < W; ++i)
        v = fmaf(alpha, v, oma * (float)blk[i / 8][i % 8]);
    v = fmaf(alpha, v, oma * (float)nrow[base + W]);
    return v;
}

// ---- chunked IIR scan + SPP + MSE, t-major fp16 planes ------------------
__global__ __launch_bounds__(256, 4)
void spp_loss_kernel(const _Float16* __restrict__ noiseP,
                     const _Float16* __restrict__ noisyP,
                     const float* __restrict__ est,
                     float* __restrict__ out,
                     float alpha)
{
    const double XI = 31.622776601683793;
    const float RATIO = (float)(1.0 + XI);
    const float COEF  = (float)(XI / (1.0 + XI));
    const float INVN  = (float)(1.0 / ((double)B_SZ * NF * TFR));

    int tid = blockIdx.x * blockDim.x + threadIdx.x;
    int f   = tid % NF;
    int rem = tid / NF;
    int c   = rem & (NCH - 1);
    int b   = rem >> 4;

    float local = 0.f;
    if (b < B_SZ) {
        const int t0   = c * CHUNKT;
        const int tend = min(TFR, t0 + CHUNKT);
        const _Float16* nrow = noiseP + ((size_t)b * NF + f) * TP;
        const _Float16* yrow = noisyP + ((size_t)b * NF + f) * TP;
        const float* erow = est + ((size_t)b * NF + f) * TFR;
        const float oma = 1.f - alpha;

        float v;
        if (t0 == 0)            v = (float)nrow[0];
        else if (t0 == CHUNKT)  v = warm_fixed<32>(nrow, 0, alpha, oma);
        else                    v = warm_fixed<48>(nrow, t0 - 48, alpha, oma);

        h8 wn8[4], wy8[4];
        #pragma unroll
        for (int i = 0; i < 4; ++i) {
            wn8[i] = *(const h8*)(nrow + t0 + i * 8);
            wy8[i] = *(const h8*)(yrow + t0 + i * 8);
        }
        float last_n = (float)nrow[t0 + 32];
        float last_y = (float)yrow[t0 + 32];
        float qe[32];
        #pragma unroll
        for (int i = 0; i < 32; ++i)
            qe[i] = erow[min(t0 + 1 + i, TFR - 1)];

        {
            float np = (float)wy8[0][0];
            float e0 = erow[t0];
            float expo = -np / (v + EPS_F) * COEF;
            float spp  = 1.f / fmaf(RATIO, __expf(expo), 1.f);
            float d = e0 - spp;
            local = fmaf(d, d, local);
        }
        #pragma unroll
        for (int i = 0; i < 32; ++i) {
            int t = t0 + 1 + i;
            float nv = (i < 31) ? (float)wn8[(i + 1) / 8][(i + 1) % 8] : last_n;
            v = fmaf(alpha, v, oma * nv);
            if (t < tend) {
                float yv = (i < 31) ? (float)wy8[(i + 1) / 8][(i + 1) % 8] : last_y;
                float expo = -yv / (v + EPS_F) * COEF;
                float spp  = 1.f / fmaf(RATIO, __expf(expo), 1.f);
                float d = qe[i] - spp;
                local = fmaf(d, d, local);
            }
        }
    }

    for (int off = 32; off > 0; off >>= 1)
        local += __shfl_down(local, off);
    __shared__ float wsum[4];
    if ((threadIdx.x & 63) == 0) wsum[threadIdx.x >> 6] = local;
    __syncthreads();
    if (threadIdx.x == 0) {
        float ssum = (wsum[0] + wsum[1]) + (wsum[2] + wsum[3]);
        atomicAdd(out, ssum * INVN);
    }
}

extern "C" void kernel_launch(void* const* d_in, const int* in_sizes, int n_in,
                              void* d_out, int out_size, void* d_ws, size_t ws_size,
                              hipStream_t stream) {
    const float* est  = (const float*)d_in[0];   // spp_estimate (B,1,F,T)
    const float* sig  = (const float*)d_in[1];   // input_sig    (B,1,N)
    const float* intf = (const float*)d_in[2];   // interference (B,1,N)

    unsigned short* Bt = (unsigned short*)d_ws;                 // 512 KB basis
    _Float16* powp = (_Float16*)((char*)d_ws + (size_t)512 * 1024);

    hipLaunchKernelGGL(build_basis, dim3(512), dim3(256), 0, stream, Bt);
    hipMemsetAsync(d_out, 0, sizeof(float), stream);

    dim3 gG(16, 64, 2);
    hipLaunchKernelGGL(dft_gemm, gG, dim3(512), 0, stream,
                       sig, intf, Bt, powp);

    const double alpha_d = exp(-((double)256) / (16000.0 * 0.072));
    const _Float16* noiseP = powp;                            // sb 0..63
    const _Float16* noisyP = powp + (size_t)B_SZ * FPOW * TP; // sb 64..127
    dim3 gB((B_SZ * NCH * NF + 255) / 256);
    hipLaunchKernelGGL(spp_loss_kernel, gB, dim3(256), 0, stream,
                       noiseP, noisyP, est, (float*)d_out, (float)alpha_d);
}

// Round 19
// 91.498 us; speedup vs baseline: 1.0987x; 1.0837x over previous
//
#include <hip/hip_runtime.h>
#include <hip/hip_bf16.h>
#include <math.h>

typedef __attribute__((ext_vector_type(8))) short bf16x8;
typedef __attribute__((ext_vector_type(4))) float f32x4;
typedef __attribute__((ext_vector_type(8))) _Float16 h8;
typedef unsigned long long u64;

#define NSAMP  128000
#define TFR    501
#define TP     512         // padded t-stride of power planes
#define FPOW   257
#define NF     257
#define B_SZ   64
#define CHUNKT 32
#define NCH    16
#define EPS_F  1.1920928955078125e-07f

#define SEG    16640       // 64*256 + 256 samples per 64-frame chunk
#define SEGB   33280       // SEG * 2 bytes (bf16)
#define BPHB   32768       // one K=32 phase of basis: 512 cols = 32 KB

// ---- basis, layout [ph(16)][colgrp(32)][lane(64)][8 bf16] ---------------
// col = colgrp*16 + (lane&15); k = ph*32 + (lane>>4)*8 + j.
// col semantic: (bin>>4)*32 + isIm*16 + (bin&15); col 16 = Nyquist basis.
__global__ __launch_bounds__(256)
void build_basis(unsigned short* __restrict__ Bt) {
    int col = blockIdx.x;
    int g = col >> 5, o = col & 15;
    int isIm = (col >> 4) & 1;
    int bin = g * 16 + o;
    for (int k = threadIdx.x; k < 512; k += 256) {
        float w = sinf((float)k * (float)(M_PI / 512.0));   // sqrt-hann
        float v;
        if (col == 16) {
            v = w * ((k & 1) ? -1.f : 1.f);
        } else {
            int mm = (bin * k) & 511;
            float th = (float)mm * (float)(2.0 * M_PI / 512.0);
            v = w * (isIm ? -sinf(th) : cosf(th));
        }
        __hip_bfloat16 h = __float2bfloat16(v);
        int ph = k >> 5, kq = (k >> 3) & 3, j = k & 7;
        size_t idx = (((size_t)ph * 32 + (col >> 4)) * 64
                      + kq * 16 + (col & 15)) * 8 + j;
        Bt[idx] = *reinterpret_cast<unsigned short*>(&h);
    }
}

// ---- MFMA DFT GEMM v19: both signals per block (fixed-cost amortization) -
// grid (8 mchunk, 64 b) = 512 blocks = exactly 2 blocks/CU x 256 CU -> ONE
// residency round. Per block: 2 sequential passes (intf, sig), each = r16's
// {stage A 33KB -> barrier-free 16-phase K-loop (B from L2, ping-pong
// prefetch) -> t-major fp16 epilogue}. Tests the F(fixed) vs W(work) split:
// if per-block fixed cost dominates, dur ~ F+2W ~= 0.6x of r16's 2-round.
__global__ __launch_bounds__(512)
void dft_gemm(const float* __restrict__ sig,
              const float* __restrict__ intf,
              const unsigned short* __restrict__ Bt,
              _Float16* __restrict__ powo)
{
    __shared__ char As[SEGB];

    const int mchunk = blockIdx.x, b = blockIdx.y;
    const int tid = threadIdx.x, lane = tid & 63, wn = tid >> 6;  // 8 waves
    const int lq = lane >> 4, ll = lane & 15;
    const int tbase = mchunk * 16384 - 256;

    // per-lane byte base into basis for this wave's 4 col-groups
    const char* bb = (const char*)Bt + (size_t)(wn * 4 * 64 + lane) * 16;

    for (int s = 0; s < 2; ++s) {
        const float* x = (s == 0 ? intf : sig) + (size_t)b * NSAMP;

        // ---- A staging: contiguous segment, float4, bf16, XOR swizzle ----
        {
            const int jlo = (tbase < 0) ? -tbase : 0;
            const int jhi = (tbase + SEG > NSAMP) ? (NSAMP - tbase) : SEG;
            for (int i = tid; i < SEG / 4; i += 512) {
                int j = i * 4;
                float f0, f1, f2, f3;
                if (j >= jlo && j + 4 <= jhi) {
                    float4 v = *(const float4*)(x + tbase + j);
                    f0 = v.x; f1 = v.y; f2 = v.z; f3 = v.w;
                } else {
                    int p0 = tbase + j;
                    int pp[4];
                    #pragma unroll
                    for (int e = 0; e < 4; ++e) {
                        int p = p0 + e;
                        if (p < 0) p = -p;
                        if (p >= NSAMP) p = 2 * NSAMP - 2 - p;
                        pp[e] = p;
                    }
                    f0 = x[pp[0]]; f1 = x[pp[1]]; f2 = x[pp[2]]; f3 = x[pp[3]];
                }
                unsigned short h[4];
                __hip_bfloat16 t0 = __float2bfloat16(f0); h[0] = *(unsigned short*)&t0;
                __hip_bfloat16 t1 = __float2bfloat16(f1); h[1] = *(unsigned short*)&t1;
                __hip_bfloat16 t2 = __float2bfloat16(f2); h[2] = *(unsigned short*)&t2;
                __hip_bfloat16 t3 = __float2bfloat16(f3); h[3] = *(unsigned short*)&t3;
                u64 pk = (u64)h[0] | ((u64)h[1] << 16) |
                         ((u64)h[2] << 32) | ((u64)h[3] << 48);
                int a = i * 8;
                a ^= ((a >> 9) & 7) << 4;
                *(u64*)(As + a) = pk;
            }
        }
        __syncthreads();   // A(s) ready; K-loop free-runs

        f32x4 acc[4][4];
        #pragma unroll
        for (int i = 0; i < 4; ++i)
            #pragma unroll
            for (int j = 0; j < 4; ++j) acc[i][j] = 0;

        bf16x8 B0[4], B1[4];

        auto loadPh = [&](int ph, bf16x8 (&dst)[4]) {
            const char* bp = bb + (size_t)ph * BPHB;
            #pragma unroll
            for (int nf = 0; nf < 4; ++nf)
                dst[nf] = *(const bf16x8*)(bp + nf * 1024);
        };

        auto doPhase = [&](int ph, bf16x8 (&cur)[4]) {
            bf16x8 af[4];
            #pragma unroll
            for (int mf = 0; mf < 4; ++mf) {
                int a = (mf * 16 + ll) * 512 + ph * 64 + lq * 16;
                a ^= ((a >> 9) & 7) << 4;
                af[mf] = *(const bf16x8*)(As + a);
            }
            __builtin_amdgcn_s_setprio(1);
            #pragma unroll
            for (int mf = 0; mf < 4; ++mf)
                #pragma unroll
                for (int nf = 0; nf < 4; ++nf)
                    acc[mf][nf] = __builtin_amdgcn_mfma_f32_16x16x32_bf16(
                        af[mf], cur[nf], acc[mf][nf], 0, 0, 0);
            __builtin_amdgcn_s_setprio(0);
        };

        loadPh(0, B0);
        #pragma unroll 1
        for (int pp2 = 0; pp2 < 8; ++pp2) {
            const int ph = pp2 * 2;
            loadPh(ph + 1, B1);                 // prefetch odd phase
            doPhase(ph, B0);                    // compute even phase
            if (pp2 < 7) loadPh(ph + 2, B0);    // prefetch next even phase
            doPhase(ph + 1, B1);                // compute odd phase
        }

        // ---- epilogue: power = re^2+im^2, t-major fp16, packed u64 ----
        const int sb = s * 64 + b;
        _Float16* pbase = powo + (size_t)sb * FPOW * TP;
        #pragma unroll
        for (int mf = 0; mf < 4; ++mf) {
            const int rl0 = mchunk * 64 + mf * 16 + lq * 4;
            #pragma unroll
            for (int p = 0; p < 2; ++p) {
                f32x4 re = acc[mf][2 * p], im = acc[mf][2 * p + 1];
                int gbin = wn * 2 + p;
                int bin = gbin * 16 + ll;
                bool nyq = (gbin == 0) && (ll == 0);
                unsigned short hp[4], hn[4];
                #pragma unroll
                for (int j = 0; j < 4; ++j) {
                    float pr = re[j] * re[j];
                    float pi = im[j] * im[j];
                    _Float16 hv = (_Float16)(nyq ? pr : (pr + pi));
                    hp[j] = *(unsigned short*)&hv;
                    _Float16 hw = (_Float16)pi;
                    hn[j] = *(unsigned short*)&hw;
                }
                u64 pk = (u64)hp[0] | ((u64)hp[1] << 16) |
                         ((u64)hp[2] << 32) | ((u64)hp[3] << 48);
                *(u64*)(pbase + (size_t)bin * TP + rl0) = pk;
                if (nyq) {
                    u64 pk2 = (u64)hn[0] | ((u64)hn[1] << 16) |
                              ((u64)hn[2] << 32) | ((u64)hn[3] << 48);
                    *(u64*)(pbase + (size_t)256 * TP + rl0) = pk2;
                }
            }
        }
        if (s == 0) __syncthreads();   // all waves done reading A before restage
    }
}

// ---- warm-up: vectorized fp16 loads, static indexing --------------------
template<int W>
__device__ __forceinline__ float warm_fixed(const _Float16* __restrict__ nrow,
                                            int base, float alpha, float oma) {
    h8 blk[W / 8];
    #pragma unroll
    for (int i = 0; i < W / 8; ++i)
        blk[i] = *(const h8*)(nrow + base + i * 8);
    float v = (float)blk[0][0];
    #pragma unroll
    for (int i = 1; i < W; ++i)
        v = fmaf(alpha, v, oma * (float)blk[i / 8][i % 8]);
    v = fmaf(alpha, v, oma * (float)nrow[base + W]);
    return v;
}

// ---- chunked IIR scan + SPP + MSE, t-major fp16 planes ------------------
__global__ __launch_bounds__(256, 4)
void spp_loss_kernel(const _Float16* __restrict__ noiseP,
                     const _Float16* __restrict__ noisyP,
                     const float* __restrict__ est,
                     float* __restrict__ out,
                     float alpha)
{
    const double XI = 31.622776601683793;
    const float RATIO = (float)(1.0 + XI);
    const float COEF  = (float)(XI / (1.0 + XI));
    const float INVN  = (float)(1.0 / ((double)B_SZ * NF * TFR));

    int tid = blockIdx.x * blockDim.x + threadIdx.x;
    int f   = tid % NF;
    int rem = tid / NF;
    int c   = rem & (NCH - 1);
    int b   = rem >> 4;

    float local = 0.f;
    if (b < B_SZ) {
        const int t0   = c * CHUNKT;
        const int tend = min(TFR, t0 + CHUNKT);
        const _Float16* nrow = noiseP + ((size_t)b * NF + f) * TP;
        const _Float16* yrow = noisyP + ((size_t)b * NF + f) * TP;
        const float* erow = est + ((size_t)b * NF + f) * TFR;
        const float oma = 1.f - alpha;

        float v;
        if (t0 == 0)            v = (float)nrow[0];
        else if (t0 == CHUNKT)  v = warm_fixed<32>(nrow, 0, alpha, oma);
        else                    v = warm_fixed<48>(nrow, t0 - 48, alpha, oma);

        h8 wn8[4], wy8[4];
        #pragma unroll
        for (int i = 0; i < 4; ++i) {
            wn8[i] = *(const h8*)(nrow + t0 + i * 8);
            wy8[i] = *(const h8*)(yrow + t0 + i * 8);
        }
        float last_n = (float)nrow[t0 + 32];
        float last_y = (float)yrow[t0 + 32];
        float qe[32];
        #pragma unroll
        for (int i = 0; i < 32; ++i)
            qe[i] = erow[min(t0 + 1 + i, TFR - 1)];

        {
            float np = (float)wy8[0][0];
            float e0 = erow[t0];
            float expo = -np / (v + EPS_F) * COEF;
            float spp  = 1.f / fmaf(RATIO, __expf(expo), 1.f);
            float d = e0 - spp;
            local = fmaf(d, d, local);
        }
        #pragma unroll
        for (int i = 0; i < 32; ++i) {
            int t = t0 + 1 + i;
            float nv = (i < 31) ? (float)wn8[(i + 1) / 8][(i + 1) % 8] : last_n;
            v = fmaf(alpha, v, oma * nv);
            if (t < tend) {
                float yv = (i < 31) ? (float)wy8[(i + 1) / 8][(i + 1) % 8] : last_y;
                float expo = -yv / (v + EPS_F) * COEF;
                float spp  = 1.f / fmaf(RATIO, __expf(expo), 1.f);
                float d = qe[i] - spp;
                local = fmaf(d, d, local);
            }
        }
    }

    for (int off = 32; off > 0; off >>= 1)
        local += __shfl_down(local, off);
    __shared__ float wsum[4];
    if ((threadIdx.x & 63) == 0) wsum[threadIdx.x >> 6] = local;
    __syncthreads();
    if (threadIdx.x == 0) {
        float ssum = (wsum[0] + wsum[1]) + (wsum[2] + wsum[3]);
        atomicAdd(out, ssum * INVN);
    }
}

extern "C" void kernel_launch(void* const* d_in, const int* in_sizes, int n_in,
                              void* d_out, int out_size, void* d_ws, size_t ws_size,
                              hipStream_t stream) {
    const float* est  = (const float*)d_in[0];   // spp_estimate (B,1,F,T)
    const float* sig  = (const float*)d_in[1];   // input_sig    (B,1,N)
    const float* intf = (const float*)d_in[2];   // interference (B,1,N)

    unsigned short* Bt = (unsigned short*)d_ws;                 // 512 KB basis
    _Float16* powp = (_Float16*)((char*)d_ws + (size_t)512 * 1024);

    hipLaunchKernelGGL(build_basis, dim3(512), dim3(256), 0, stream, Bt);
    hipMemsetAsync(d_out, 0, sizeof(float), stream);

    dim3 gG(8, 64);
    hipLaunchKernelGGL(dft_gemm, gG, dim3(512), 0, stream,
                       sig, intf, Bt, powp);

    const double alpha_d = exp(-((double)256) / (16000.0 * 0.072));
    const _Float16* noiseP = powp;                            // sb 0..63
    const _Float16* noisyP = powp + (size_t)B_SZ * FPOW * TP; // sb 64..127
    dim3 gB((B_SZ * NCH * NF + 255) / 256);
    hipLaunchKernelGGL(spp_loss_kernel, gB, dim3(256), 0, stream,
                       noiseP, noisyP, est, (float*)d_out, (float)alpha_d);
}